// Round 3
// baseline (52.227 us; speedup 1.0000x reference)
//
#include <hip/hip_runtime.h>
#include <float.h>

#define N_NODES_C 200000
#define HIDDEN_C 256
#define NSEG_C 1024
#define NEG_SLOPE_C 0.2f
#define NPIECE_C 4

__device__ __forceinline__ int lower_bound_dev(const int* __restrict__ b, int n, int v) {
    int lo = 0, hi = n;
    while (lo < hi) {
        int mid = (lo + hi) >> 1;
        if (b[mid] < v) lo = mid + 1; else hi = mid;
    }
    return lo;
}

// ---------------- Kernel 1: per-(segment,piece) online-softmax partial ----------------
__global__ __launch_bounds__(256, 4)
void attn_partial(const float* __restrict__ feature,
                  const float* __restrict__ a,
                  const int* __restrict__ batch,
                  float* __restrict__ ws_acc,   // [NSEG*NPIECE][HIDDEN]
                  float* __restrict__ ws_m,     // [NSEG*NPIECE]
                  float* __restrict__ ws_d) {   // [NSEG*NPIECE]
    const int b    = blockIdx.x;          // 0 .. NSEG*NPIECE-1
    const int s    = b >> 2;
    const int p    = b & 3;
    const int tid  = threadIdx.x;
    const int lane = tid & 63;
    const int wid  = tid >> 6;

    __shared__ float part[4][HIDDEN_C];
    __shared__ float md[4][2];

    const int s0  = lower_bound_dev(batch, N_NODES_C, s);
    const int s1  = lower_bound_dev(batch, N_NODES_C, s + 1);
    const int cnt = s1 - s0;

    // Balanced piece [p0, p1) of this segment.
    const int q  = cnt >> 2;
    const int r  = cnt & 3;
    const int p0 = s0 + p * q + (p < r ? p : r);
    const int p1 = p0 + q + (p < r ? 1 : 0);

    const float4 av = *reinterpret_cast<const float4*>(a + 4 * lane);

    float  m   = -FLT_MAX;
    float  d   = 0.0f;
    float4 acc = make_float4(0.f, 0.f, 0.f, 0.f);

    auto dotred = [&](const float4& f) -> float {
        float pr = f.x * av.x + f.y * av.y + f.z * av.z + f.w * av.w;
        #pragma unroll
        for (int off = 32; off >= 1; off >>= 1)
            pr += __shfl_xor(pr, off, 64);
        return (pr > 0.0f) ? pr : NEG_SLOPE_C * pr;
    };

    auto online = [&](float l, const float4& f) {
        if (l > m) {
            const float sc = __expf(m - l);   // exp(-huge)=0 on first row
            acc.x = acc.x * sc + f.x;
            acc.y = acc.y * sc + f.y;
            acc.z = acc.z * sc + f.z;
            acc.w = acc.w * sc + f.w;
            d = d * sc + 1.0f;
            m = l;
        } else {
            const float w = __expf(l - m);
            acc.x += w * f.x;
            acc.y += w * f.y;
            acc.z += w * f.z;
            acc.w += w * f.w;
            d += w;
        }
    };

    int i = p0 + wid;
    for (; i + 4 < p1; i += 8) {
        const float4 f0 = *reinterpret_cast<const float4*>(
            feature + (size_t)i * HIDDEN_C + 4 * lane);
        const float4 f1 = *reinterpret_cast<const float4*>(
            feature + (size_t)(i + 4) * HIDDEN_C + 4 * lane);
        const float l0 = dotred(f0);
        const float l1 = dotred(f1);
        online(l0, f0);
        online(l1, f1);
    }
    if (i < p1) {
        const float4 f0 = *reinterpret_cast<const float4*>(
            feature + (size_t)i * HIDDEN_C + 4 * lane);
        online(dotred(f0), f0);
    }

    // ---- Exact merge of the 4 wave partials -> one piece partial. ----
    *reinterpret_cast<float4*>(&part[wid][4 * lane]) = acc;
    if (lane == 0) { md[wid][0] = m; md[wid][1] = d; }
    __syncthreads();

    const float M  = fmaxf(fmaxf(md[0][0], md[1][0]), fmaxf(md[2][0], md[3][0]));
    // M == -FLT_MAX for an empty piece; exp(0)=1 but d=0 and acc=0, stays exact.
    const float e0 = __expf(md[0][0] - M);
    const float e1 = __expf(md[1][0] - M);
    const float e2 = __expf(md[2][0] - M);
    const float e3 = __expf(md[3][0] - M);
    const float D  = e0 * md[0][1] + e1 * md[1][1] + e2 * md[2][1] + e3 * md[3][1];
    const float v  = e0 * part[0][tid] + e1 * part[1][tid]
                   + e2 * part[2][tid] + e3 * part[3][tid];

    ws_acc[(size_t)b * HIDDEN_C + tid] = v;
    if (tid == 0) { ws_m[b] = M; ws_d[b] = D; }
}

// ---------------- Kernel 2: merge NPIECE partials per segment ----------------
__global__ __launch_bounds__(256, 4)
void attn_merge(const int* __restrict__ batch,
                const float* __restrict__ ws_acc,
                const float* __restrict__ ws_m,
                const float* __restrict__ ws_d,
                float* __restrict__ out) {
    const int s   = blockIdx.x;
    const int tid = threadIdx.x;

    const int s0  = lower_bound_dev(batch, N_NODES_C, s);
    const int s1  = lower_bound_dev(batch, N_NODES_C, s + 1);
    const int cnt = s1 - s0;

    if (cnt == 0) {
        out[(size_t)s * HIDDEN_C + tid] = 0.0f;
        return;
    }

    const int base = s * NPIECE_C;
    const float m0 = ws_m[base + 0], m1 = ws_m[base + 1];
    const float m2 = ws_m[base + 2], m3 = ws_m[base + 3];
    const float M  = fmaxf(fmaxf(m0, m1), fmaxf(m2, m3));
    const float e0 = __expf(m0 - M);   // empty piece: exp(-huge)=0
    const float e1 = __expf(m1 - M);
    const float e2 = __expf(m2 - M);
    const float e3 = __expf(m3 - M);
    const float D  = e0 * ws_d[base + 0] + e1 * ws_d[base + 1]
                   + e2 * ws_d[base + 2] + e3 * ws_d[base + 3];

    const float v = e0 * ws_acc[(size_t)(base + 0) * HIDDEN_C + tid]
                  + e1 * ws_acc[(size_t)(base + 1) * HIDDEN_C + tid]
                  + e2 * ws_acc[(size_t)(base + 2) * HIDDEN_C + tid]
                  + e3 * ws_acc[(size_t)(base + 3) * HIDDEN_C + tid];

    out[(size_t)s * HIDDEN_C + tid] = v / (D * (float)cnt);
}

// ---------------- Fallback: single-kernel one-pass (R2 version) ----------------
__global__ __launch_bounds__(256, 4)
void attn_pool_1pass(const float* __restrict__ feature,
                     const float* __restrict__ a,
                     const int* __restrict__ batch,
                     float* __restrict__ out) {
    const int s    = blockIdx.x;
    const int tid  = threadIdx.x;
    const int lane = tid & 63;
    const int wid  = tid >> 6;

    __shared__ float part[4][HIDDEN_C];
    __shared__ float md[4][2];

    const int s0  = lower_bound_dev(batch, N_NODES_C, s);
    const int s1  = lower_bound_dev(batch, N_NODES_C, s + 1);
    const int cnt = s1 - s0;

    if (cnt == 0) {
        out[(size_t)s * HIDDEN_C + tid] = 0.0f;
        return;
    }

    const float4 av = *reinterpret_cast<const float4*>(a + 4 * lane);

    float  m   = -FLT_MAX;
    float  d   = 0.0f;
    float4 acc = make_float4(0.f, 0.f, 0.f, 0.f);

    auto dotred = [&](const float4& f) -> float {
        float pr = f.x * av.x + f.y * av.y + f.z * av.z + f.w * av.w;
        #pragma unroll
        for (int off = 32; off >= 1; off >>= 1)
            pr += __shfl_xor(pr, off, 64);
        return (pr > 0.0f) ? pr : NEG_SLOPE_C * pr;
    };

    auto online = [&](float l, const float4& f) {
        if (l > m) {
            const float sc = __expf(m - l);
            acc.x = acc.x * sc + f.x;
            acc.y = acc.y * sc + f.y;
            acc.z = acc.z * sc + f.z;
            acc.w = acc.w * sc + f.w;
            d = d * sc + 1.0f;
            m = l;
        } else {
            const float w = __expf(l - m);
            acc.x += w * f.x;
            acc.y += w * f.y;
            acc.z += w * f.z;
            acc.w += w * f.w;
            d += w;
        }
    };

    int i = s0 + wid;
    for (; i + 4 < s1; i += 8) {
        const float4 f0 = *reinterpret_cast<const float4*>(
            feature + (size_t)i * HIDDEN_C + 4 * lane);
        const float4 f1 = *reinterpret_cast<const float4*>(
            feature + (size_t)(i + 4) * HIDDEN_C + 4 * lane);
        const float l0 = dotred(f0);
        const float l1 = dotred(f1);
        online(l0, f0);
        online(l1, f1);
    }
    if (i < s1) {
        const float4 f0 = *reinterpret_cast<const float4*>(
            feature + (size_t)i * HIDDEN_C + 4 * lane);
        online(dotred(f0), f0);
    }

    *reinterpret_cast<float4*>(&part[wid][4 * lane]) = acc;
    if (lane == 0) { md[wid][0] = m; md[wid][1] = d; }
    __syncthreads();

    const float M  = fmaxf(fmaxf(md[0][0], md[1][0]), fmaxf(md[2][0], md[3][0]));
    const float e0 = __expf(md[0][0] - M);
    const float e1 = __expf(md[1][0] - M);
    const float e2 = __expf(md[2][0] - M);
    const float e3 = __expf(md[3][0] - M);
    const float D  = e0 * md[0][1] + e1 * md[1][1] + e2 * md[2][1] + e3 * md[3][1];

    const float v = e0 * part[0][tid] + e1 * part[1][tid]
                  + e2 * part[2][tid] + e3 * part[3][tid];
    out[(size_t)s * HIDDEN_C + tid] = v / (D * (float)cnt);
}

extern "C" void kernel_launch(void* const* d_in, const int* in_sizes, int n_in,
                              void* d_out, int out_size, void* d_ws, size_t ws_size,
                              hipStream_t stream) {
    const float* feature = (const float*)d_in[0];
    const float* a       = (const float*)d_in[1];
    const int*   batch   = (const int*)d_in[2];
    float* out = (float*)d_out;
    (void)in_sizes; (void)n_in; (void)out_size;

    const size_t nPart    = (size_t)NSEG_C * NPIECE_C;            // 4096
    const size_t accBytes = nPart * HIDDEN_C * sizeof(float);     // 4 MB
    const size_t needed   = accBytes + 2 * nPart * sizeof(float); // +32 KB

    if (ws_size >= needed) {
        float* ws_acc = (float*)d_ws;
        float* ws_m   = ws_acc + nPart * HIDDEN_C;
        float* ws_d   = ws_m + nPart;
        attn_partial<<<(int)nPart, 256, 0, stream>>>(feature, a, batch,
                                                     ws_acc, ws_m, ws_d);
        attn_merge<<<NSEG_C, 256, 0, stream>>>(batch, ws_acc, ws_m, ws_d, out);
    } else {
        attn_pool_1pass<<<NSEG_C, 256, 0, stream>>>(feature, a, batch, out);
    }
}

// Round 4
// 41.161 us; speedup vs baseline: 1.2688x; 1.2688x over previous
//
#include <hip/hip_runtime.h>
#include <float.h>

#define N_NODES_C 200000
#define HIDDEN_C 256
#define NSEG_C 1024
#define NEG_SLOPE_C 0.2f
#define NWAVE_C 8

__device__ __forceinline__ int lower_bound_dev(const int* __restrict__ b, int n, int v) {
    int lo = 0, hi = n;
    while (lo < hi) {
        int mid = (lo + hi) >> 1;
        if (b[mid] < v) lo = mid + 1; else hi = mid;
    }
    return lo;
}

// One block per segment; 8 waves; 32 waves/CU for max memory-level parallelism.
__global__ __launch_bounds__(512, 8)
void attn_pool_1pass(const float* __restrict__ feature,
                     const float* __restrict__ a,
                     const int* __restrict__ batch,
                     float* __restrict__ out) {
    const int s    = blockIdx.x;
    const int tid  = threadIdx.x;
    const int lane = tid & 63;
    const int wid  = tid >> 6;          // 0..7

    __shared__ float part[NWAVE_C][HIDDEN_C];
    __shared__ float md[NWAVE_C][2];    // per-wave {max, denom}

    const int s0  = lower_bound_dev(batch, N_NODES_C, s);
    const int s1  = lower_bound_dev(batch, N_NODES_C, s + 1);
    const int cnt = s1 - s0;

    if (cnt == 0) {
        if (tid < HIDDEN_C) out[(size_t)s * HIDDEN_C + tid] = 0.0f;
        return;
    }

    // Lane owns columns 4*lane .. 4*lane+3.
    const float4 av = *reinterpret_cast<const float4*>(a + 4 * lane);

    float  m   = -FLT_MAX;
    float  d   = 0.0f;
    float4 acc = make_float4(0.f, 0.f, 0.f, 0.f);

    auto ldrow = [&](int i) -> float4 {
        return *reinterpret_cast<const float4*>(feature + (size_t)i * HIDDEN_C + 4 * lane);
    };

    auto dotred = [&](const float4& f) -> float {
        float p = f.x * av.x + f.y * av.y + f.z * av.z + f.w * av.w;
        #pragma unroll
        for (int off = 32; off >= 1; off >>= 1)
            p += __shfl_xor(p, off, 64);
        return (p > 0.0f) ? p : NEG_SLOPE_C * p;
    };

    auto online = [&](float l, const float4& f) {
        if (l > m) {                    // wave-uniform branch
            const float sc = __expf(m - l);   // exp(-inf)=0 on first row
            acc.x = acc.x * sc + f.x;
            acc.y = acc.y * sc + f.y;
            acc.z = acc.z * sc + f.z;
            acc.w = acc.w * sc + f.w;
            d = d * sc + 1.0f;
            m = l;
        } else {
            const float w = __expf(l - m);
            acc.x += w * f.x;
            acc.y += w * f.y;
            acc.z += w * f.z;
            acc.w += w * f.w;
            d += w;
        }
    };

    // Wave wid handles rows s0+wid :: 8. Software pipeline: issue next pair
    // of loads before consuming the current pair.
    int i = s0 + wid;
    if (i + NWAVE_C < s1) {
        float4 f0 = ldrow(i);
        float4 f1 = ldrow(i + NWAVE_C);
        i += 2 * NWAVE_C;
        for (; i + NWAVE_C < s1; i += 2 * NWAVE_C) {
            const float4 nf0 = ldrow(i);
            const float4 nf1 = ldrow(i + NWAVE_C);
            const float l0 = dotred(f0);
            const float l1 = dotred(f1);
            online(l0, f0);
            online(l1, f1);
            f0 = nf0;
            f1 = nf1;
        }
        const float l0 = dotred(f0);
        const float l1 = dotred(f1);
        online(l0, f0);
        online(l1, f1);
    }
    if (i < s1) {
        const float4 f = ldrow(i);
        online(dotred(f), f);
    }

    // ---- Exact merge of the 8 wave partials. ----
    *reinterpret_cast<float4*>(&part[wid][4 * lane]) = acc;
    if (lane == 0) { md[wid][0] = m; md[wid][1] = d; }
    __syncthreads();

    if (tid < HIDDEN_C) {
        float M = md[0][0];
        #pragma unroll
        for (int k = 1; k < NWAVE_C; ++k) M = fmaxf(M, md[k][0]);

        float D = 0.0f;
        float v = 0.0f;
        #pragma unroll
        for (int k = 0; k < NWAVE_C; ++k) {
            const float e = __expf(md[k][0] - M);   // empty wave: exp(-huge)=0
            D += e * md[k][1];
            v += e * part[k][tid];
        }
        out[(size_t)s * HIDDEN_C + tid] = v / (D * (float)cnt);
    }
}

extern "C" void kernel_launch(void* const* d_in, const int* in_sizes, int n_in,
                              void* d_out, int out_size, void* d_ws, size_t ws_size,
                              hipStream_t stream) {
    const float* feature = (const float*)d_in[0];
    const float* a       = (const float*)d_in[1];
    const int*   batch   = (const int*)d_in[2];
    float* out = (float*)d_out;
    (void)in_sizes; (void)n_in; (void)out_size; (void)d_ws; (void)ws_size;

    attn_pool_1pass<<<NSEG_C, 512, 0, stream>>>(feature, a, batch, out);
}